// Round 1
// baseline (113.220 us; speedup 1.0000x reference)
//
#include <hip/hip_runtime.h>

// Normalized_Graph_expand: out[n, k, :] = feat[g[n,k], :] - feat[n, :]
// B=1, N=25000, F=128, CUT=32 (F, CUT hard-coded; N derived from in_sizes).
//
// One block (256 threads) per node:
//   c = tid & 31  -> float4 column group (covers F=128 as 32 x float4)
//   r = tid >> 5  -> neighbor rows r, r+8, r+16, r+24
// Center float4 loaded once per thread and reused for all 4 neighbor rows.

__global__ __launch_bounds__(256) void ngx_kernel(
    const float* __restrict__ feat,   // [N, 128]
    const int*   __restrict__ graph,  // [N, 32]
    float*       __restrict__ out,    // [N, 32, 128]
    int N)
{
    const int node = blockIdx.x;
    if (node >= N) return;

    const int tid = threadIdx.x;
    const int c = tid & 31;   // float4 column index within a row
    const int r = tid >> 5;   // base neighbor row (0..7)

    const float4* fc = reinterpret_cast<const float4*>(feat + (size_t)node * 128);
    const float4 center = fc[c];

    const int* g = graph + (size_t)node * 32;
    float4* o = reinterpret_cast<float4*>(out + (size_t)node * 32 * 128);

#pragma unroll
    for (int j = 0; j < 4; ++j) {
        const int nb  = r + j * 8;
        const int idx = g[nb];  // broadcast across the 32 lanes of this row
        const float4 v =
            reinterpret_cast<const float4*>(feat + (size_t)idx * 128)[c];
        float4 d;
        d.x = v.x - center.x;
        d.y = v.y - center.y;
        d.z = v.z - center.z;
        d.w = v.w - center.w;
        o[(size_t)nb * 32 + c] = d;
    }
}

extern "C" void kernel_launch(void* const* d_in, const int* in_sizes, int n_in,
                              void* d_out, int out_size, void* d_ws, size_t ws_size,
                              hipStream_t stream) {
    const float* feat  = (const float*)d_in[0];
    const int*   graph = (const int*)d_in[1];
    float*       out   = (float*)d_out;

    const int N = in_sizes[1] / 32;  // x_graph is [1, N, 32]

    ngx_kernel<<<N, 256, 0, stream>>>(feat, graph, out, N);
}

// Round 3
// 108.113 us; speedup vs baseline: 1.0472x; 1.0472x over previous
//
#include <hip/hip_runtime.h>

// Normalized_Graph_expand: out[n, k, :] = feat[g[n,k], :] - feat[n, :]
// B=1, N=25000, F=128, CUT=32 (F, CUT hard-coded; N derived from in_sizes).
//
// One block (256 threads) per node:
//   c = tid & 31  -> float4 column group (covers F=128 as 32 x float4)
//   r = tid >> 5  -> neighbor rows r, r+8, r+16, r+24
// Center float4 loaded once per thread and reused for all 4 neighbor rows.
//
// Output stores are nontemporal (native clang vector type, not HIP float4 —
// the builtin rejects HIP_vector_type): the 410 MB output stream is never
// re-read, and letting it allocate in L2 evicts the 12.8 MB feature table
// that the random gather needs resident (logical gather volume ~410 MB).

typedef float f32x4 __attribute__((ext_vector_type(4)));

__global__ __launch_bounds__(256) void ngx_kernel(
    const float* __restrict__ feat,   // [N, 128]
    const int*   __restrict__ graph,  // [N, 32]
    float*       __restrict__ out,    // [N, 32, 128]
    int N)
{
    const int node = blockIdx.x;
    if (node >= N) return;

    const int tid = threadIdx.x;
    const int c = tid & 31;   // float4 column index within a row
    const int r = tid >> 5;   // base neighbor row (0..7)

    const f32x4* fc = reinterpret_cast<const f32x4*>(feat + (size_t)node * 128);
    const f32x4 center = fc[c];

    const int* g = graph + (size_t)node * 32;
    f32x4* o = reinterpret_cast<f32x4*>(out + (size_t)node * 32 * 128);

#pragma unroll
    for (int j = 0; j < 4; ++j) {
        const int nb  = r + j * 8;
        const int idx = g[nb];  // broadcast across the 32 lanes of this row
        const f32x4 v =
            reinterpret_cast<const f32x4*>(feat + (size_t)idx * 128)[c];
        const f32x4 d = v - center;
        __builtin_nontemporal_store(d, &o[(size_t)nb * 32 + c]);
    }
}

extern "C" void kernel_launch(void* const* d_in, const int* in_sizes, int n_in,
                              void* d_out, int out_size, void* d_ws, size_t ws_size,
                              hipStream_t stream) {
    const float* feat  = (const float*)d_in[0];
    const int*   graph = (const int*)d_in[1];
    float*       out   = (float*)d_out;

    const int N = in_sizes[1] / 32;  // x_graph is [1, N, 32]

    ngx_kernel<<<N, 256, 0, stream>>>(feat, graph, out, N);
}